// Round 1
// 4736.879 us; speedup vs baseline: 1.3521x; 1.3521x over previous
//
#include <hip/hip_runtime.h>
#include <hip/hip_bf16.h>

// Sizes: T=256, B=2048, NC=3, NM=125, IN=128, H=256, 4H=1024, K_gates=384
// Weight-stationary partition: 256 WGs x 512 thr. WG = (s = h-col slice 0..7, r = row block 0..31).
//   - gate-weight slice (384K x 128 gate cols, interleaved i/f/g/o for h cols [32s,32s+32)) lives in LDS: 98 KB
//   - out-proj slice (256K x 16 out cols [16s,16s+16)) in LDS: 8 KB
//   - per step: h(t+1)/x(t+1) exchanged among the 8 slice-WGs of a row block via global bf16
//     buffers + 2 device-scope 8-WG flag barriers (monotonic counters, leader spin).
constexpr int TSTEPS = 255;
constexpr int XROW   = 392;   // LDS x|h row stride (shorts): [x 0..127 | h 128..383] + 8 pad (784 B, 16B-aligned)

typedef __attribute__((ext_vector_type(8))) short short8;
typedef __attribute__((ext_vector_type(4))) float f32x4;

__device__ __forceinline__ unsigned short f2bf(float f) {
    __hip_bfloat16 h = __float2bfloat16(f);
    return *reinterpret_cast<unsigned short*>(&h);
}
__device__ __forceinline__ float bf2f(unsigned short u) {
    __hip_bfloat16 h;
    *reinterpret_cast<unsigned short*>(&h) = u;
    return __bfloat162float(h);
}
__device__ __forceinline__ float sigf(float x) {
    return __builtin_amdgcn_rcpf(1.f + __expf(-x));
}
__device__ __forceinline__ float tanh_fast(float x) {
    x = fminf(fmaxf(x, -15.f), 15.f);
    float e = __expf(-2.f * x);
    return (1.f - e) * __builtin_amdgcn_rcpf(1.f + e);
}

// 8-WG group barrier: monotonic counter, leader release-add + relaxed spin + acquire fence.
// __syncthreads() before the add drains every wave's stores (vmcnt(0) at s_barrier), so the
// agent-release writeback covers the whole WG's stores; the acquire fence invalidates stale
// L1/L2 lines before any post-barrier load (cross-XCD safe).
__device__ __forceinline__ void groupbar(unsigned int* cnt, unsigned int tgt, int tid) {
    __syncthreads();
    if (tid == 0) {
        __builtin_amdgcn_fence(__ATOMIC_RELEASE, "agent");
        __hip_atomic_fetch_add(cnt, 1u, __ATOMIC_RELAXED, __HIP_MEMORY_SCOPE_AGENT);
        while (__hip_atomic_load(cnt, __ATOMIC_RELAXED, __HIP_MEMORY_SCOPE_AGENT) < tgt)
            __builtin_amdgcn_s_sleep(1);
        __builtin_amdgcn_fence(__ATOMIC_ACQUIRE, "agent");
    }
    __syncthreads();
}

// ---------------------------------------------------------------------------
// Prep: pack weights to bf16 MFMA B-fragment order, slice-major; fuse biases; zero flags.
// Gate pack (393216): idx = ((((s*2+ch)*4+q)*12+kt)*64+l)*8+j
//   n = q*256 + s*32 + ch*16 + (l&15);  k = kt*32 + (l>>4)*8 + j  (k<128: W_ih else W_hh)
// Out pack (32768): idx = (((s*8+kt)*64+l)*8+j
//   n = s*16 + (l&15) (n<3: W_cat else W_val);  k = kt*32 + (l>>4)*8 + j
// ---------------------------------------------------------------------------
__global__ void prep_kernel(const float* __restrict__ Wih, const float* __restrict__ Whh,
                            const float* __restrict__ bih, const float* __restrict__ bhh,
                            const float* __restrict__ Wcat, const float* __restrict__ bcat,
                            const float* __restrict__ Wval, const float* __restrict__ bval,
                            unsigned short* __restrict__ Wg, unsigned short* __restrict__ Wo,
                            float* __restrict__ bg, float* __restrict__ bo,
                            unsigned int* __restrict__ flags) {
    int idx = blockIdx.x * 256 + threadIdx.x;
    if (idx < 393216) {
        int j   = idx & 7;
        int l   = (idx >> 3) & 63;
        int t12 = idx >> 9;
        int kt  = t12 % 12;
        int u   = t12 / 12;            // u = s*8 + ch*4 + q
        int q = u & 3, ch = (u >> 2) & 1, s = u >> 3;
        int n = q * 256 + s * 32 + ch * 16 + (l & 15);
        int k = kt * 32 + (l >> 4) * 8 + j;
        float v = (k < 128) ? Wih[n * 128 + k] : Whh[n * 256 + (k - 128)];
        Wg[idx] = f2bf(v);
    } else if (idx < 425984) {
        int i2 = idx - 393216;
        int j = i2 & 7, l = (i2 >> 3) & 63, kt = (i2 >> 9) & 7, s = i2 >> 12;
        int n = s * 16 + (l & 15);
        int k = kt * 32 + (l >> 4) * 8 + j;
        float v = (n < 3) ? Wcat[n * 256 + k] : Wval[(n - 3) * 256 + k];
        Wo[i2] = f2bf(v);
    } else if (idx < 427008) {
        int i3 = idx - 425984;
        bg[i3] = bih[i3] + bhh[i3];
    } else if (idx < 427136) {
        int i4 = idx - 427008;
        bo[i4] = (i4 < 3) ? bcat[i4] : bval[i4 - 3];
    } else if (idx < 428160) {
        flags[idx - 427136] = 0u;      // barrier counters (re-zeroed every launch/replay)
    }
}

// ---------------------------------------------------------------------------
// Main persistent kernel: grid=256 (1 WG/CU guaranteed by 157 KB LDS), 512 threads.
// wgid = s*32 + r  (slice in high bits -> the 8 group members share an XCD under %8 placement).
// ---------------------------------------------------------------------------
__global__ __launch_bounds__(512) void rnn_kernel(
    const float* __restrict__ seq,
    const unsigned short* __restrict__ Wg, const unsigned short* __restrict__ Wo,
    const float* __restrict__ bg, const float* __restrict__ bo,
    unsigned short* __restrict__ hb, unsigned short* __restrict__ xb,
    unsigned int* __restrict__ flags, float* __restrict__ out) {

    __shared__ __align__(16) unsigned short xh[64][XROW];   // 50176 B: [x(128) | h(256)] per row
    __shared__ __align__(16) unsigned short wlds[49152];    // 98304 B: gate-weight slice
    __shared__ __align__(16) unsigned short wolds[4096];    //  8192 B: out-proj slice
    __shared__ __align__(16) float sqlds[64][16];           //  4096 B: seq[t+1] slice (f32)
    // total LDS = 160768 B <= 163840

    const int tid = threadIdx.x;
    const int wv = tid >> 6, l = tid & 63;
    const int gq = l >> 4, ml = l & 15;
    const int s  = blockIdx.x >> 5;        // col slice 0..7
    const int r  = blockIdx.x & 31;        // row block 0..31
    const int row0 = r * 64;

    unsigned int* cntA = flags + r * 32;   // 64B-padded counters per row block
    unsigned int* cntB = cntA + 16;

    // ---- one-time: stage weight slices into LDS ----
    {
        const short8* srcg = reinterpret_cast<const short8*>(Wg + (size_t)s * 49152);
        short8* dstg = reinterpret_cast<short8*>(wlds);
#pragma unroll
        for (int i = 0; i < 12; ++i) dstg[i * 512 + tid] = srcg[i * 512 + tid];
        reinterpret_cast<short8*>(wolds)[tid] =
            reinterpret_cast<const short8*>(Wo + (size_t)s * 4096)[tid];
    }
    // ---- x(0) = bf16(seq[0]) (NaN-free), h(0) = 0 ----
#pragma unroll
    for (int i = 0; i < 4; ++i) {
        int c = i * 512 + tid;             // 2048 float4 chunks
        int row = c >> 5, c4 = c & 31;
        f32x4 v = *reinterpret_cast<const f32x4*>(seq + (size_t)(row0 + row) * 128 + c4 * 4);
        unsigned short* p = &xh[row][c4 * 4];
        p[0] = f2bf(v[0]); p[1] = f2bf(v[1]); p[2] = f2bf(v[2]); p[3] = f2bf(v[3]);
    }
    {
        short8 z = {0, 0, 0, 0, 0, 0, 0, 0};
#pragma unroll
        for (int i = 0; i < 4; ++i) {
            int c = i * 512 + tid;         // 2048 short8 chunks (h region)
            int row = c >> 5, k8 = c & 31;
            *reinterpret_cast<short8*>(&xh[row][128 + k8 * 8]) = z;
        }
    }

    // wave decomposition: gates wave = (mt = wv>>1, ch = wv&1); thread owns h-col s*32+ch*16+ml
    const int mt = wv >> 1, ch = wv & 1;
    float bgq[4];
#pragma unroll
    for (int q = 0; q < 4; ++q) bgq[q] = bg[q * 256 + s * 32 + ch * 16 + ml];
    const float obv = bo[s * 16 + ml];     // out-proj bias (waves 0-3)
    float cst[4] = {0.f, 0.f, 0.f, 0.f};   // c-state: 4 rows x 1 col per thread

    const unsigned short* xrow = &xh[mt * 16 + ml][0];
    const unsigned short* wb   = wlds + (size_t)(ch * 4) * 12 * 512 + l * 8;
    unsigned short* hdst = hb + (size_t)(row0 + mt * 16 + gq * 4) * 256 + s * 32 + ch * 16 + ml;

    __syncthreads();

    for (int t = 0; t < TSTEPS; ++t) {
        // ---- A: gates = [x|h] @ Wslice^T + b   (48 MFMA / wave, weights from LDS) ----
        f32x4 acc[4];
#pragma unroll
        for (int q = 0; q < 4; ++q) { f32x4 z = {bgq[q], bgq[q], bgq[q], bgq[q]}; acc[q] = z; }
#pragma unroll
        for (int kt = 0; kt < 12; ++kt) {
            short8 a = *reinterpret_cast<const short8*>(xrow + kt * 32 + gq * 8);
#pragma unroll
            for (int q = 0; q < 4; ++q) {
                short8 b = *reinterpret_cast<const short8*>(wb + (q * 12 + kt) * 512);
                acc[q] = __builtin_amdgcn_mfma_f32_16x16x32_bf16(a, b, acc[q], 0, 0, 0);
            }
        }
        // ---- B: LSTM elementwise (in-lane), write h(t+1) slice -> global ----
#pragma unroll
        for (int rr = 0; rr < 4; ++rr) {
            float cn = sigf(acc[1][rr]) * cst[rr] + sigf(acc[0][rr]) * tanh_fast(acc[2][rr]);
            float hn = sigf(acc[3][rr]) * tanh_fast(cn);
            cst[rr] = cn;
            hdst[(size_t)rr * 256] = f2bf(hn);
        }
        groupbar(cntA, 8u * (t + 1), tid);     // all 8 slices published h(t+1)
        // ---- stage full h(t+1) row-block -> LDS ----
#pragma unroll
        for (int i = 0; i < 4; ++i) {
            int c = i * 512 + tid;             // 2048 short8 chunks
            int row = c >> 5, k8 = c & 31;
            short8 v = *reinterpret_cast<const short8*>(hb + (size_t)(row0 + row) * 256 + k8 * 8);
            *reinterpret_cast<short8*>(&xh[row][128 + k8 * 8]) = v;
        }
        __syncthreads();
        // ---- C: out-proj (waves 0-3, 8 MFMA) | seq[t+1] slice prefetch (waves 4-7) ----
        f32x4 a2 = {obv, obv, obv, obv};
        if (wv < 4) {
#pragma unroll
            for (int kt = 0; kt < 8; ++kt) {
                short8 a = *reinterpret_cast<const short8*>(&xh[wv * 16 + ml][128 + kt * 32 + gq * 8]);
                short8 b = *reinterpret_cast<const short8*>(wolds + kt * 512 + l * 8);
                a2 = __builtin_amdgcn_mfma_f32_16x16x32_bf16(a, b, a2, 0, 0, 0);
            }
        } else if (t < TSTEPS - 1) {
            int tid2 = tid & 255;
#pragma unroll
            for (int i = 0; i < 4; ++i) {
                int c = i * 256 + tid2;        // 1024 float4 chunks (64 rows x 16 cols)
                int row = c >> 2, c4 = c & 3;
                f32x4 v = *reinterpret_cast<const f32x4*>(
                    seq + ((size_t)(t + 1) * 2048 + row0 + row) * 128 + s * 16 + c4 * 4);
                *reinterpret_cast<f32x4*>(&sqlds[row][c4 * 4]) = v;
            }
        }
        __syncthreads();
        // ---- D/E: +i_val passthrough, softmax (slice 0), store out, impute x(t+1) slice ----
        if (wv < 4) {
            const int nout = s * 16 + ml;
            float vv[4];
#pragma unroll
            for (int rr = 0; rr < 4; ++rr) {
                float v = a2[rr];
                if (nout >= 3) v += bf2f(xh[wv * 16 + gq * 4 + rr][nout]);   // i_val = x(t)[nout]
                vv[rr] = v;
            }
            if (s == 0) {
#pragma unroll
                for (int rr = 0; rr < 4; ++rr) {
                    float v0 = __shfl(vv[rr], (l & 48) + 0);
                    float v1 = __shfl(vv[rr], (l & 48) + 1);
                    float v2 = __shfl(vv[rr], (l & 48) + 2);
                    if (ml < 3) {
                        float mx = fmaxf(fmaxf(v0, v1), v2);
                        float e0 = __expf(v0 - mx), e1 = __expf(v1 - mx), e2 = __expf(v2 - mx);
                        float en = (ml == 0) ? e0 : ((ml == 1) ? e1 : e2);
                        vv[rr] = en * __builtin_amdgcn_rcpf(e0 + e1 + e2);
                    }
                }
            }
            size_t ob0 = ((size_t)t * 2048 + row0 + wv * 16 + gq * 4) * 128 + nout;
#pragma unroll
            for (int rr = 0; rr < 4; ++rr) {
                out[ob0 + (size_t)rr * 128] = vv[rr];
                if (t < TSTEPS - 1) {
                    float sv = sqlds[wv * 16 + gq * 4 + rr][ml];
                    float xv = (sv != sv) ? vv[rr] : sv;   // isnan -> model output
                    xb[(size_t)(row0 + wv * 16 + gq * 4 + rr) * 128 + nout] = f2bf(xv);
                }
            }
        }
        if (t < TSTEPS - 1) {
            groupbar(cntB, 8u * (t + 1), tid); // all 8 slices published x(t+1)
            // ---- stage full x(t+1) row-block -> LDS ----
#pragma unroll
            for (int i = 0; i < 2; ++i) {
                int c = i * 512 + tid;         // 1024 short8 chunks
                int row = c >> 4, k8 = c & 15;
                short8 v = *reinterpret_cast<const short8*>(xb + (size_t)(row0 + row) * 128 + k8 * 8);
                *reinterpret_cast<short8*>(&xh[row][k8 * 8]) = v;
            }
            __syncthreads();
        }
    }
}

// ---------------------------------------------------------------------------
extern "C" void kernel_launch(void* const* d_in, const int* in_sizes, int n_in,
                              void* d_out, int out_size, void* d_ws, size_t ws_size,
                              hipStream_t stream) {
    const float* seq  = (const float*)d_in[0];
    const float* Wih  = (const float*)d_in[1];
    const float* Whh  = (const float*)d_in[2];
    const float* bih  = (const float*)d_in[3];
    const float* bhh  = (const float*)d_in[4];
    const float* Wcat = (const float*)d_in[5];
    const float* bcat = (const float*)d_in[6];
    const float* Wval = (const float*)d_in[7];
    const float* bval = (const float*)d_in[8];

    char* ws = (char*)d_ws;
    unsigned short* Wg    = (unsigned short*)(ws);                 // 786432 B
    unsigned short* Wo    = (unsigned short*)(ws + 786432);        //  65536 B
    float*          bg    = (float*)(ws + 851968);                 //   4096 B
    float*          bo    = (float*)(ws + 856064);                 //    512 B
    unsigned int*   flags = (unsigned int*)(ws + 856576);          //   4096 B
    unsigned short* hbuf  = (unsigned short*)(ws + 860672);        // 1048576 B  (h exchange, bf16)
    unsigned short* xbuf  = (unsigned short*)(ws + 1909248);       //  524288 B  (x exchange, bf16)
    // total ws use: 2433536 B

    prep_kernel<<<1673, 256, 0, stream>>>(Wih, Whh, bih, bhh, Wcat, bcat, Wval, bval,
                                          Wg, Wo, bg, bo, flags);
    rnn_kernel<<<256, 512, 0, stream>>>(seq, Wg, Wo, bg, bo, hbuf, xbuf, flags, (float*)d_out);
}

// Round 2
// 1716.922 us; speedup vs baseline: 3.7303x; 2.7589x over previous
//
#include <hip/hip_runtime.h>
#include <hip/hip_bf16.h>

// Sizes: T=256, B=2048, NC=3, NM=125, IN=128, H=256, 4H=1024, K_gates=384
// 256 WGs x 512 thr. WG = (s = h-col slice 0..7, r = row block 0..31), rows [64r, 64r+64).
//  - gate-weight slice (384K x 128 interleaved i/f/g/o gate cols) in LDS: 96 KB
//  - out-proj weights (full 128 cols, 32x32x16 B-frags) in 64 VGPRs/thread
//  - per step: ONLY h is exchanged among the 8 slice-WGs of a row block, via sc0/sc1
//    coherent accesses + one relaxed agent-scope flag barrier. No L2-wide fences.
//    h buffers are double-buffered by step parity. Out-proj/softmax/imputation are
//    computed redundantly per WG (cheap) so x(t+1) never leaves the CU.
constexpr int TSTEPS = 255;
constexpr int XROW   = 392;   // LDS x|h row stride (shorts): [x 0..127 | h 128..383] + 8 pad

typedef __attribute__((ext_vector_type(8))) short short8;
typedef __attribute__((ext_vector_type(4))) float f32x4;
typedef __attribute__((ext_vector_type(16))) float f32x16;
typedef __attribute__((ext_vector_type(4))) int i32x4;

__device__ __forceinline__ unsigned short f2bf(float f) {
    __hip_bfloat16 h = __float2bfloat16(f);
    return *reinterpret_cast<unsigned short*>(&h);
}
__device__ __forceinline__ float bf2f(unsigned short u) {
    __hip_bfloat16 h;
    *reinterpret_cast<unsigned short*>(&h) = u;
    return __bfloat162float(h);
}
__device__ __forceinline__ float sigf(float x) {
    return __builtin_amdgcn_rcpf(1.f + __expf(-x));
}
__device__ __forceinline__ float tanh_fast(float x) {
    x = fminf(fmaxf(x, -15.f), 15.f);
    float e = __expf(-2.f * x);
    return (1.f - e) * __builtin_amdgcn_rcpf(1.f + e);
}

// Coherent (cross-XCD) accesses: sc0 sc1 = read/write the device coherent point,
// bypassing non-coherent L1/L2. No cache-wide fences needed.
__device__ __forceinline__ i32x4 load_coh16(const void* p) {
    i32x4 r;
    asm volatile("global_load_dwordx4 %0, %1, off sc0 sc1" : "=v"(r) : "v"(p) : "memory");
    return r;
}
__device__ __forceinline__ void store_coh_u16(void* p, unsigned short v) {
    unsigned int vv = v;
    asm volatile("global_store_short %0, %1, off sc0 sc1" :: "v"(p), "v"(vv) : "memory");
}

// 8-WG group barrier: explicit vmcnt drain (covers the inline-asm coherent stores,
// which the compiler's waitcnt pass does not track) -> syncthreads -> leader
// relaxed agent-scope add + poll -> syncthreads.
__device__ __forceinline__ void groupbar(unsigned int* cnt, unsigned int tgt, int tid) {
    asm volatile("s_waitcnt vmcnt(0)" ::: "memory");
    __syncthreads();
    if (tid == 0) {
        __hip_atomic_fetch_add(cnt, 1u, __ATOMIC_RELAXED, __HIP_MEMORY_SCOPE_AGENT);
        while (__hip_atomic_load(cnt, __ATOMIC_RELAXED, __HIP_MEMORY_SCOPE_AGENT) < tgt)
            __builtin_amdgcn_s_sleep(1);
    }
    __syncthreads();
}

// ---------------------------------------------------------------------------
// Prep: pack weights to bf16 MFMA fragment order; fuse biases; zero flags.
// Gate pack (393216, 16x16x32 B-frags): idx = ((((s*2+ch)*4+q)*12+kt)*64+l)*8+j
//   n = q*256 + s*32 + ch*16 + (l&15);  k = kt*32 + (l>>4)*8 + j  (k<128: W_ih else W_hh)
// Out pack (32768, 32x32x16 B-frags): idx = (((nt2*16+kt)*64+l)*8+j
//   n = nt2*32 + (l&31) (n<3: W_cat else W_val);  k = kt*16 + (l>>5)*8 + j
// ---------------------------------------------------------------------------
__global__ void prep_kernel(const float* __restrict__ Wih, const float* __restrict__ Whh,
                            const float* __restrict__ bih, const float* __restrict__ bhh,
                            const float* __restrict__ Wcat, const float* __restrict__ bcat,
                            const float* __restrict__ Wval, const float* __restrict__ bval,
                            unsigned short* __restrict__ Wg, unsigned short* __restrict__ Wo,
                            float* __restrict__ bg, float* __restrict__ bo,
                            unsigned int* __restrict__ flags) {
    int idx = blockIdx.x * 256 + threadIdx.x;
    if (idx < 393216) {
        int j   = idx & 7;
        int l   = (idx >> 3) & 63;
        int t12 = idx >> 9;
        int kt  = t12 % 12;
        int u   = t12 / 12;            // u = s*8 + ch*4 + q
        int q = u & 3, ch = (u >> 2) & 1, s = u >> 3;
        int n = q * 256 + s * 32 + ch * 16 + (l & 15);
        int k = kt * 32 + (l >> 4) * 8 + j;
        float v = (k < 128) ? Wih[n * 128 + k] : Whh[n * 256 + (k - 128)];
        Wg[idx] = f2bf(v);
    } else if (idx < 425984) {
        int i2 = idx - 393216;
        int j = i2 & 7, ll = (i2 >> 3) & 63, kt = (i2 >> 9) & 15, nt2 = i2 >> 13;
        int n = nt2 * 32 + (ll & 31);
        int k = kt * 16 + (ll >> 5) * 8 + j;
        float v = (n < 3) ? Wcat[n * 256 + k] : Wval[(n - 3) * 256 + k];
        Wo[i2] = f2bf(v);
    } else if (idx < 427008) {
        int i3 = idx - 425984;
        bg[i3] = bih[i3] + bhh[i3];
    } else if (idx < 427136) {
        int i4 = idx - 427008;
        bo[i4] = (i4 < 3) ? bcat[i4] : bval[i4 - 3];
    } else if (idx < 428160) {
        flags[idx - 427136] = 0u;      // barrier counters (re-zeroed every launch/replay)
    }
}

// ---------------------------------------------------------------------------
// Main persistent kernel: grid=256 (1 WG/CU via 145 KB LDS), 512 threads.
// ---------------------------------------------------------------------------
__global__ __launch_bounds__(512, 2) void rnn_kernel(
    const float* __restrict__ seq,
    const unsigned short* __restrict__ Wg, const unsigned short* __restrict__ Wo,
    const float* __restrict__ bg, const float* __restrict__ bo,
    unsigned short* __restrict__ hb, unsigned int* __restrict__ flags,
    float* __restrict__ out) {

    __shared__ __align__(16) unsigned short xh[64][XROW];   // 50176 B: [x(128) | h(256)] per row
    __shared__ __align__(16) unsigned short wlds[49152];    // 98304 B: gate-weight slice

    const int tid = threadIdx.x;
    const int wv  = tid >> 6, l = tid & 63;
    const int gq  = l >> 4, ml = l & 15;
    const int s   = blockIdx.x >> 5;       // col slice 0..7
    const int r   = blockIdx.x & 31;       // row block 0..31
    const int row0 = r * 64;

    unsigned int* cnt = flags + r * 16;    // 64B-spaced counter per group

    // ---- one-time: gate weight slice -> LDS ----
    {
        const short8* srcg = reinterpret_cast<const short8*>(Wg + (size_t)s * 49152);
        short8* dstg = reinterpret_cast<short8*>(wlds);
#pragma unroll
        for (int i = 0; i < 12; ++i) dstg[i * 512 + tid] = srcg[i * 512 + tid];
    }

    // ---- persistent out-proj B-frags in VGPRs (wave owns N-tile nt2) ----
    const int mt2 = wv >> 2, nt2 = wv & 3;
    const int cl = l & 31, lh = l >> 5;
    short8 wof[16];
    {
        const short8* WoV = reinterpret_cast<const short8*>(Wo);
#pragma unroll
        for (int kt = 0; kt < 16; ++kt) wof[kt] = WoV[(nt2 * 16 + kt) * 64 + l];
    }

    // ---- x(0) = bf16(seq[0]) (NaN-free), h(0) = 0 ----
#pragma unroll
    for (int i = 0; i < 4; ++i) {
        int c = i * 512 + tid;
        int row = c >> 5, c4 = c & 31;
        f32x4 v = *reinterpret_cast<const f32x4*>(seq + (size_t)(row0 + row) * 128 + c4 * 4);
        unsigned short* p = &xh[row][c4 * 4];
        p[0] = f2bf(v[0]); p[1] = f2bf(v[1]); p[2] = f2bf(v[2]); p[3] = f2bf(v[3]);
    }
    {
        short8 z = {0, 0, 0, 0, 0, 0, 0, 0};
#pragma unroll
        for (int i = 0; i < 4; ++i) {
            int c = i * 512 + tid;
            int row = c >> 5, k8 = c & 31;
            *reinterpret_cast<short8*>(&xh[row][128 + k8 * 8]) = z;
        }
    }

    // gate decomposition: wave = (mt = wv>>1, ch = wv&1); thread owns h-col s*32+ch*16+ml
    const int mt = wv >> 1, ch = wv & 1;
    float bgq[4];
#pragma unroll
    for (int q = 0; q < 4; ++q) bgq[q] = bg[q * 256 + s * 32 + ch * 16 + ml];
    const int ocol = nt2 * 32 + cl;        // out-proj column (per thread, 32x32 D layout)
    const float obv = bo[ocol];
    float cst[4] = {0.f, 0.f, 0.f, 0.f};

    const unsigned short* xrow = &xh[mt * 16 + ml][0];
    const unsigned short* wb   = wlds + (ch * 4) * 12 * 512 + l * 8;

    int orow[16];                          // out-proj rows (32x32 D: (i&3)+8*(i>>2)+4*lh)
#pragma unroll
    for (int i = 0; i < 16; ++i) orow[i] = mt2 * 32 + (i & 3) + 8 * (i >> 2) + 4 * lh;

    __syncthreads();

    for (int t = 0; t < TSTEPS; ++t) {
        // ---- A: gates = [x|h] @ Wslice^T + b  (48 MFMA / wave, B-frags from LDS) ----
        f32x4 acc[4];
#pragma unroll
        for (int q = 0; q < 4; ++q) { f32x4 z = {bgq[q], bgq[q], bgq[q], bgq[q]}; acc[q] = z; }
#pragma unroll
        for (int kt = 0; kt < 12; ++kt) {
            short8 a = *reinterpret_cast<const short8*>(xrow + kt * 32 + gq * 8);
#pragma unroll
            for (int q = 0; q < 4; ++q) {
                short8 b = *reinterpret_cast<const short8*>(wb + (q * 12 + kt) * 512);
                acc[q] = __builtin_amdgcn_mfma_f32_16x16x32_bf16(a, b, acc[q], 0, 0, 0);
            }
        }

        // ---- B: LSTM elementwise; coherent store of h(t+1) slice (parity buffer) ----
        unsigned short* hbt = hb + (size_t)(t & 1) * 524288 + (size_t)r * 16384 + (size_t)s * 2048;
#pragma unroll
        for (int rr = 0; rr < 4; ++rr) {
            float cn = sigf(acc[1][rr]) * cst[rr] + sigf(acc[0][rr]) * tanh_fast(acc[2][rr]);
            float hn = sigf(acc[3][rr]) * tanh_fast(cn);
            cst[rr] = cn;
            store_coh_u16(hbt + (mt * 16 + gq * 4 + rr) * 32 + ch * 16 + ml, f2bf(hn));
        }

        // ---- prefetch seq[t+1] into regs (latency hides under the barrier) ----
        float sv[16];
        if (t < TSTEPS - 1) {
            const float* sp = seq + ((size_t)(t + 1) * 2048 + row0) * 128 + ocol;
#pragma unroll
            for (int i = 0; i < 16; ++i) sv[i] = sp[(size_t)orow[i] * 128];
        }

        groupbar(cnt, 8u * (t + 1), tid);  // all 8 slices published h(t+1)

        // ---- restage full h(t+1) row-block: coherent 16B loads -> LDS ----
        {
            const unsigned short* hsrc = hb + (size_t)(t & 1) * 524288 + (size_t)r * 16384;
            i32x4 hv[4];
#pragma unroll
            for (int i = 0; i < 4; ++i) {
                int c = i * 512 + tid;     // 2048 chunks: s2 = c>>8, row = (c>>2)&63, half = c&3
                hv[i] = load_coh16(hsrc + (c >> 8) * 2048 + ((c >> 2) & 63) * 32 + (c & 3) * 8);
            }
            asm volatile("s_waitcnt vmcnt(0)" ::: "memory");
            __builtin_amdgcn_sched_barrier(0);
#pragma unroll
            for (int i = 0; i < 4; ++i) {
                int c = i * 512 + tid;
                *reinterpret_cast<i32x4*>(&xh[(c >> 2) & 63][128 + (c >> 8) * 32 + (c & 3) * 8]) = hv[i];
            }
        }
        __syncthreads();

        // ---- C: out-proj, FULL 128 cols per WG (32x32x16, B-frags in regs) ----
        f32x16 acc2;
#pragma unroll
        for (int i = 0; i < 16; ++i) acc2[i] = obv;
#pragma unroll
        for (int kt = 0; kt < 16; ++kt) {
            short8 a = *reinterpret_cast<const short8*>(&xh[mt2 * 32 + cl][128 + kt * 16 + lh * 8]);
            acc2 = __builtin_amdgcn_mfma_f32_32x32x16_bf16(a, wof[kt], acc2, 0, 0, 0);
        }

        // ---- D: + i_val passthrough, softmax over 3 cat cols (lanes cl<3, nt2==0) ----
        float vv[16];
#pragma unroll
        for (int i = 0; i < 16; ++i) {
            float v = acc2[i];
            if (ocol >= 3) v += bf2f(xh[orow[i]][ocol]);   // i_val = x(t)[row][ocol]
            vv[i] = v;
        }
        if (nt2 == 0) {
#pragma unroll
            for (int i = 0; i < 16; ++i) {
                float v0 = __shfl(vv[i], (l & 32) + 0);
                float v1 = __shfl(vv[i], (l & 32) + 1);
                float v2 = __shfl(vv[i], (l & 32) + 2);
                if (cl < 3) {
                    float mx = fmaxf(fmaxf(v0, v1), v2);
                    float e0 = __expf(v0 - mx), e1 = __expf(v1 - mx), e2 = __expf(v2 - mx);
                    float en = (cl == 0) ? e0 : ((cl == 1) ? e1 : e2);
                    vv[i] = en * __builtin_amdgcn_rcpf(e0 + e1 + e2);
                }
            }
        }

        // ---- E: store own 16-col out slice; impute x(t+1) locally into LDS ----
        if (nt2 == (s >> 1) && (cl >> 4) == (s & 1)) {     // ocol in [16s, 16s+16)
            size_t ob0 = ((size_t)t * 2048 + row0) * 128 + ocol;
#pragma unroll
            for (int i = 0; i < 16; ++i) out[ob0 + (size_t)orow[i] * 128] = vv[i];
        }
        if (t < TSTEPS - 1) {
#pragma unroll
            for (int i = 0; i < 16; ++i) {
                float sq = sv[i];
                xh[orow[i]][ocol] = f2bf((sq != sq) ? vv[i] : sq);   // isnan -> model output
            }
        }
        __syncthreads();
    }
}

// ---------------------------------------------------------------------------
extern "C" void kernel_launch(void* const* d_in, const int* in_sizes, int n_in,
                              void* d_out, int out_size, void* d_ws, size_t ws_size,
                              hipStream_t stream) {
    const float* seq  = (const float*)d_in[0];
    const float* Wih  = (const float*)d_in[1];
    const float* Whh  = (const float*)d_in[2];
    const float* bih  = (const float*)d_in[3];
    const float* bhh  = (const float*)d_in[4];
    const float* Wcat = (const float*)d_in[5];
    const float* bcat = (const float*)d_in[6];
    const float* Wval = (const float*)d_in[7];
    const float* bval = (const float*)d_in[8];

    char* ws = (char*)d_ws;
    unsigned short* Wg    = (unsigned short*)(ws);                 //  786432 B
    unsigned short* Wo    = (unsigned short*)(ws + 786432);        //   65536 B
    float*          bgp   = (float*)(ws + 851968);                 //    4096 B
    float*          bop   = (float*)(ws + 856064);                 //     512 B
    unsigned int*   flags = (unsigned int*)(ws + 856576);          //    4096 B
    unsigned short* hbuf  = (unsigned short*)(ws + 860672);        // 2097152 B (2 parity buffers)
    // total ws use: 2957824 B

    prep_kernel<<<1673, 256, 0, stream>>>(Wih, Whh, bih, bhh, Wcat, bcat, Wval, bval,
                                          Wg, Wo, bgp, bop, flags);
    rnn_kernel<<<256, 512, 0, stream>>>(seq, Wg, Wo, bgp, bop, hbuf, flags, (float*)d_out);
}

// Round 3
// 1122.794 us; speedup vs baseline: 5.7042x; 1.5292x over previous
//
#include <hip/hip_runtime.h>
#include <hip/hip_bf16.h>

// Sizes: T=256, B=2048, NC=3, NM=125, IN=128, H=256, 4H=1024, K_gates=384
// 256 WGs x 512 thr. WG = (s = h-col slice 0..7, r = row block 0..31), rows [64r, 64r+64).
// TRANSPOSED GEMMs: gates^T = Wg.[x|h]^T, out^T = Wo.h^T  (32x32x16 MFMA).
//  - ALL weights live in VGPRs as A-fragments (gate slice: 24 frags = 96 VGPR,
//    out-proj full 128 cols: 16 frags = 64 VGPR). Zero weight traffic per step.
//  - B-fragments = x|h rows, contiguous ds_read_b128 from LDS.
//  - D: lane = one batch row x 16 packed cols. Gate packing puts all 4 gates of an
//    h-col in-lane (LSTM register-local); out packing gives 4-contiguous col chunks
//    (in-lane softmax, reg-resident i_val, dwordx4 stores, b64 impute writes).
//  - per step: ONLY h exchanged among the 8 slice-WGs of a row block (sc0/sc1
//    coherent accesses + one relaxed agent-scope flag barrier, parity dbuf).
constexpr int TSTEPS = 255;
constexpr int XROW   = 392;   // LDS x|h row stride (shorts): [x 0..127 | h 128..383] + 8 pad

typedef __attribute__((ext_vector_type(8))) short short8;
typedef __attribute__((ext_vector_type(4))) float f32x4;
typedef __attribute__((ext_vector_type(16))) float f32x16;
typedef __attribute__((ext_vector_type(4))) int i32x4;
typedef __attribute__((ext_vector_type(2))) unsigned int u32x2;

__device__ __forceinline__ unsigned short f2bf(float f) {
    __hip_bfloat16 h = __float2bfloat16(f);
    return *reinterpret_cast<unsigned short*>(&h);
}
__device__ __forceinline__ float bf2f(unsigned short u) {
    __hip_bfloat16 h;
    *reinterpret_cast<unsigned short*>(&h) = u;
    return __bfloat162float(h);
}
__device__ __forceinline__ float sigf(float x) {
    return __builtin_amdgcn_rcpf(1.f + __expf(-x));
}
__device__ __forceinline__ float tanh_fast(float x) {
    x = fminf(fmaxf(x, -15.f), 15.f);
    float e = __expf(-2.f * x);
    return (1.f - e) * __builtin_amdgcn_rcpf(1.f + e);
}

// Coherent (cross-XCD) accesses: sc0 sc1 bypass non-coherent caches.
__device__ __forceinline__ i32x4 load_coh16(const void* p) {
    i32x4 r;
    asm volatile("global_load_dwordx4 %0, %1, off sc0 sc1" : "=v"(r) : "v"(p) : "memory");
    return r;
}
__device__ __forceinline__ void store_coh16(void* p, i32x4 v) {
    asm volatile("global_store_dwordx4 %0, %1, off sc0 sc1" :: "v"(p), "v"(v) : "memory");
}

// 8-WG group barrier: vmcnt drain (covers inline-asm coherent stores) -> syncthreads
// -> leader relaxed agent-scope add + poll -> syncthreads.
__device__ __forceinline__ void groupbar(unsigned int* cnt, unsigned int tgt, int tid) {
    asm volatile("s_waitcnt vmcnt(0)" ::: "memory");
    __syncthreads();
    if (tid == 0) {
        __hip_atomic_fetch_add(cnt, 1u, __ATOMIC_RELAXED, __HIP_MEMORY_SCOPE_AGENT);
        while (__hip_atomic_load(cnt, __ATOMIC_RELAXED, __HIP_MEMORY_SCOPE_AGENT) < tgt)
            __builtin_amdgcn_s_sleep(1);
    }
    __syncthreads();
}

// ---------------------------------------------------------------------------
// Prep: pack weights to bf16 MFMA A-fragment order; fuse biases; zero flags.
// Gate pack (393216, 32x32x16 A-frags, pcol m = lane&31 within m-tile gm):
//   idx = (((s*4+gm)*24+kt)*64+l)*8+j;  pm = l&31
//   gate = pm&3, h_local = gm*8 + (pm>>2);  n = gate*256 + s*32 + h_local
//   k = kt*16 + (l>>5)*8 + j   (k<128: W_ih else W_hh)
// Out pack (32768, 32x32x16 A-frags): idx = ((om*16+kt)*64+l)*8+j
//   oc = om*32 + (l&31) (oc<3: W_cat else W_val);  k = kt*16 + (l>>5)*8 + j
// ---------------------------------------------------------------------------
__global__ void prep_kernel(const float* __restrict__ Wih, const float* __restrict__ Whh,
                            const float* __restrict__ bih, const float* __restrict__ bhh,
                            const float* __restrict__ Wcat, const float* __restrict__ bcat,
                            const float* __restrict__ Wval, const float* __restrict__ bval,
                            unsigned short* __restrict__ Wg, unsigned short* __restrict__ Wo,
                            float* __restrict__ bg, float* __restrict__ bo,
                            unsigned int* __restrict__ flags) {
    int idx = blockIdx.x * 256 + threadIdx.x;
    if (idx < 393216) {
        int j   = idx & 7;
        int l   = (idx >> 3) & 63;
        int t24 = idx >> 9;
        int kt  = t24 % 24;
        int u   = t24 / 24;            // s*4 + gm
        int gm = u & 3, ss = u >> 2;
        int pm = l & 31;
        int n  = (pm & 3) * 256 + ss * 32 + gm * 8 + (pm >> 2);
        int k  = kt * 16 + (l >> 5) * 8 + j;
        float v = (k < 128) ? Wih[n * 128 + k] : Whh[n * 256 + (k - 128)];
        Wg[idx] = f2bf(v);
    } else if (idx < 425984) {
        int i2 = idx - 393216;
        int j = i2 & 7, ll = (i2 >> 3) & 63, kt = (i2 >> 9) & 15, om = i2 >> 13;
        int n = om * 32 + (ll & 31);
        int k = kt * 16 + (ll >> 5) * 8 + j;
        float v = (n < 3) ? Wcat[n * 256 + k] : Wval[(n - 3) * 256 + k];
        Wo[i2] = f2bf(v);
    } else if (idx < 427008) {
        int i3 = idx - 425984;
        bg[i3] = bih[i3] + bhh[i3];
    } else if (idx < 427136) {
        int i4 = idx - 427008;
        bo[i4] = (i4 < 3) ? bcat[i4] : bval[i4 - 3];
    } else if (idx < 428160) {
        flags[idx - 427136] = 0u;      // barrier counters (re-zeroed every launch/replay)
    }
}

// ---------------------------------------------------------------------------
// Main persistent kernel: grid=256 (1 WG/CU forced via 84 KB LDS), 512 threads.
// ---------------------------------------------------------------------------
__global__ __launch_bounds__(512, 2) void rnn_kernel(
    const float* __restrict__ seq,
    const unsigned short* __restrict__ Wg, const unsigned short* __restrict__ Wo,
    const float* __restrict__ bg, const float* __restrict__ bo,
    unsigned short* __restrict__ hb, unsigned int* __restrict__ flags,
    float* __restrict__ out) {

    __shared__ __align__(16) unsigned short xh[64][XROW];   // 50176 B: [x(128) | h(256)] per row
    __shared__ __align__(16) float bgl[128];                // permuted gate bias
    __shared__ __align__(16) float obl[128];                // permuted out bias
    extern __shared__ char lds_pad[];                       // +32768 B at launch -> 1 WG/CU
    (void)lds_pad;

    const int tid = threadIdx.x;
    const int wv  = tid >> 6, l = tid & 63;
    const int c   = l & 31, lh = l >> 5;
    const int s   = blockIdx.x >> 5;       // col slice 0..7
    const int r   = blockIdx.x & 31;       // row block 0..31
    const int row0 = r * 64;
    const int hm  = wv >> 1;               // m-tile: gm for gates, om for out-proj
    const int bn  = wv & 1;                // row half
    const int R   = bn * 32 + c;           // local batch row 0..63

    unsigned int* cnt = flags + r * 16;

    // ---- persistent weight A-fragments in VGPRs ----
    short8 wga[24], woa[16];
    {
        const short8* WgV = reinterpret_cast<const short8*>(Wg);
        const short8* WoV = reinterpret_cast<const short8*>(Wo);
#pragma unroll
        for (int kt = 0; kt < 24; ++kt) wga[kt] = WgV[(size_t)(((s * 4 + hm) * 24 + kt) * 64) + l];
#pragma unroll
        for (int kt = 0; kt < 16; ++kt) woa[kt] = WoV[(size_t)((hm * 16 + kt) * 64) + l];
    }

    // ---- permuted biases -> LDS (per-lane-class contiguous, broadcast reads) ----
    if (tid < 128) {
        int gm_ = tid >> 5, lh_ = (tid >> 4) & 1, i_ = tid & 15;
        int pm = (i_ & 3) + 8 * (i_ >> 2) + 4 * lh_;
        bgl[tid] = bg[(pm & 3) * 256 + s * 32 + gm_ * 8 + (pm >> 2)];
        obl[tid] = bo[gm_ * 32 + 8 * (i_ >> 2) + 4 * lh_ + (i_ & 3)];
    }

    // ---- x(0) = bf16(seq[0]) (NaN-free), h(0) = 0 ----
#pragma unroll
    for (int i = 0; i < 4; ++i) {
        int ch = i * 512 + tid;
        int row = ch >> 5, c4 = ch & 31;
        f32x4 v = *reinterpret_cast<const f32x4*>(seq + (size_t)(row0 + row) * 128 + c4 * 4);
        unsigned short* p = &xh[row][c4 * 4];
        p[0] = f2bf(v[0]); p[1] = f2bf(v[1]); p[2] = f2bf(v[2]); p[3] = f2bf(v[3]);
    }
    {
        short8 z = {0, 0, 0, 0, 0, 0, 0, 0};
#pragma unroll
        for (int i = 0; i < 4; ++i) {
            int ch = i * 512 + tid;
            int row = ch >> 5, k8 = ch & 31;
            *reinterpret_cast<short8*>(&xh[row][128 + k8 * 8]) = z;
        }
    }

    // ---- xv = reg-resident bf16 x(t) at lane's 16 cols (base hm*32+8g'+4lh) ----
    unsigned int xv[8];
    {
        const float* sp0 = seq + (size_t)(row0 + R) * 128 + hm * 32 + 4 * lh;
#pragma unroll
        for (int g = 0; g < 4; ++g) {
            f32x4 v = *reinterpret_cast<const f32x4*>(sp0 + 8 * g);
            xv[2 * g]     = (unsigned int)f2bf(v[0]) | ((unsigned int)f2bf(v[1]) << 16);
            xv[2 * g + 1] = (unsigned int)f2bf(v[2]) | ((unsigned int)f2bf(v[3]) << 16);
        }
    }

    float cst[4] = {0.f, 0.f, 0.f, 0.f};
    const float* bgp = &bgl[(hm * 2 + lh) * 16];
    const float* obp = &obl[(hm * 2 + lh) * 16];
    const unsigned short* xrow = &xh[R][0];

    __syncthreads();

    for (int t = 0; t < TSTEPS; ++t) {
        // ---- prefetch seq[t+1] (consumed after the barrier; hides HBM latency) ----
        f32x4 sq[4];
        if (t < TSTEPS - 1) {
            const float* sp = seq + ((size_t)(t + 1) * 2048 + row0 + R) * 128 + hm * 32 + 4 * lh;
#pragma unroll
            for (int g = 0; g < 4; ++g) sq[g] = *reinterpret_cast<const f32x4*>(sp + 8 * g);
        }

        // ---- A: gates^T = Wg.[x|h]^T + b   (24 MFMA / wave, weights in regs) ----
        f32x16 acc;
#pragma unroll
        for (int i = 0; i < 16; ++i) acc[i] = bgp[i];
#pragma unroll
        for (int kt = 0; kt < 24; ++kt) {
            short8 b = *reinterpret_cast<const short8*>(xrow + kt * 16 + lh * 8);
            acc = __builtin_amdgcn_mfma_f32_32x32x16_bf16(wga[kt], b, acc, 0, 0, 0);
        }

        // ---- B: LSTM (in-lane: acc[4g'+{0,1,2,3}] = i,f,g,o of h-col gm*8+2g'+lh) ----
        float hn[4];
#pragma unroll
        for (int g = 0; g < 4; ++g) {
            float cn = sigf(acc[4 * g + 1]) * cst[g] + sigf(acc[4 * g]) * tanh_fast(acc[4 * g + 2]);
            hn[g] = sigf(acc[4 * g + 3]) * tanh_fast(cn);
            cst[g] = cn;
        }
        // pack pairs across lh halves -> cols [s*32+hm*8, +8) of row R, one dwordx4
        {
            i32x4 hw;
#pragma unroll
            for (int g = 0; g < 4; ++g) {
                float other = __shfl_xor(hn[g], 32);
                unsigned short lo = f2bf(lh ? other : hn[g]);
                unsigned short hi = f2bf(lh ? hn[g] : other);
                hw[g] = (int)((unsigned int)lo | ((unsigned int)hi << 16));
            }
            if (lh == 0) {
                char* hp = (char*)hb + (size_t)(t & 1) * 1048576 + (size_t)r * 32768
                         + (size_t)R * 512 + s * 64 + hm * 16;
                store_coh16(hp, hw);
            }
        }

        groupbar(cnt, 8u * (t + 1), tid);      // all 8 slices published h(t+1)

        // ---- restage full h(t+1) row-block: coherent 16B loads -> LDS ----
        {
            const unsigned short* hsrc = hb + (size_t)(t & 1) * 524288 + (size_t)r * 16384;
            i32x4 hv[4];
#pragma unroll
            for (int i = 0; i < 4; ++i) {
                int ch = i * 512 + tid;        // Rl = ch>>5, c16 = ch&31
                hv[i] = load_coh16(hsrc + (size_t)((ch >> 5) * 256 + (ch & 31) * 8));
            }
            asm volatile("s_waitcnt vmcnt(0)" ::: "memory");
            __builtin_amdgcn_sched_barrier(0);
#pragma unroll
            for (int i = 0; i < 4; ++i) {
                int ch = i * 512 + tid;
                *reinterpret_cast<i32x4*>(&xh[ch >> 5][128 + (ch & 31) * 8]) = hv[i];
            }
        }
        __syncthreads();

        // ---- C: out^T = Wo.h^T + b  (16 MFMA / wave, weights in regs) ----
        f32x16 acc2;
#pragma unroll
        for (int i = 0; i < 16; ++i) acc2[i] = obp[i];
#pragma unroll
        for (int kt = 0; kt < 16; ++kt) {
            short8 b = *reinterpret_cast<const short8*>(xrow + 128 + kt * 16 + lh * 8);
            acc2 = __builtin_amdgcn_mfma_f32_32x32x16_bf16(woa[kt], b, acc2, 0, 0, 0);
        }

        // ---- D: + i_val (reg-resident), in-lane softmax over cols 0..2 ----
        float vv[16];
#pragma unroll
        for (int g = 0; g < 4; ++g) {
#pragma unroll
            for (int j = 0; j < 4; ++j) {
                int i = 4 * g + j;
                float v = acc2[i];
                unsigned short x16 = (unsigned short)(xv[2 * g + (j >> 1)] >> ((j & 1) * 16));
                bool isCat = (g == 0) && (j < 3) && ((hm | lh) == 0);
                if (!isCat) v += bf2f(x16);
                vv[i] = v;
            }
        }
        if ((hm | lh) == 0) {
            float mx = fmaxf(fmaxf(vv[0], vv[1]), vv[2]);
            float e0 = __expf(vv[0] - mx), e1 = __expf(vv[1] - mx), e2 = __expf(vv[2] - mx);
            float rs = __builtin_amdgcn_rcpf(e0 + e1 + e2);
            vv[0] = e0 * rs; vv[1] = e1 * rs; vv[2] = e2 * rs;
        }

        // ---- E: store own out slice (cols [16s,16s+16)); impute x(t+1) locally ----
        if (hm == (s >> 1)) {
            int gp = (s & 1) * 2;
            size_t ob0 = ((size_t)t * 2048 + row0 + R) * 128 + hm * 32 + 4 * lh;
            f32x4 o0 = {vv[4 * gp], vv[4 * gp + 1], vv[4 * gp + 2], vv[4 * gp + 3]};
            f32x4 o1 = {vv[4 * gp + 4], vv[4 * gp + 5], vv[4 * gp + 6], vv[4 * gp + 7]};
            *reinterpret_cast<f32x4*>(out + ob0 + 8 * gp) = o0;
            *reinterpret_cast<f32x4*>(out + ob0 + 8 * gp + 8) = o1;
        }
        if (t < TSTEPS - 1) {
#pragma unroll
            for (int g = 0; g < 4; ++g) {
                unsigned int w0 = 0, w1 = 0;
#pragma unroll
                for (int j = 0; j < 4; ++j) {
                    unsigned short s16 = f2bf(sq[g][j]);
                    bool nan = (s16 & 0x7fff) > 0x7f80;
                    unsigned short nv = nan ? f2bf(vv[4 * g + j]) : s16;
                    if (j < 2) w0 |= (unsigned int)nv << (16 * j);
                    else       w1 |= (unsigned int)nv << (16 * (j - 2));
                }
                xv[2 * g] = w0; xv[2 * g + 1] = w1;
                u32x2 wp = {w0, w1};
                *reinterpret_cast<u32x2*>(&xh[R][hm * 32 + 8 * g + 4 * lh]) = wp;
            }
        }
        __syncthreads();
    }
}

// ---------------------------------------------------------------------------
extern "C" void kernel_launch(void* const* d_in, const int* in_sizes, int n_in,
                              void* d_out, int out_size, void* d_ws, size_t ws_size,
                              hipStream_t stream) {
    const float* seq  = (const float*)d_in[0];
    const float* Wih  = (const float*)d_in[1];
    const float* Whh  = (const float*)d_in[2];
    const float* bih  = (const float*)d_in[3];
    const float* bhh  = (const float*)d_in[4];
    const float* Wcat = (const float*)d_in[5];
    const float* bcat = (const float*)d_in[6];
    const float* Wval = (const float*)d_in[7];
    const float* bval = (const float*)d_in[8];

    char* ws = (char*)d_ws;
    unsigned short* Wg    = (unsigned short*)(ws);                 //  786432 B
    unsigned short* Wo    = (unsigned short*)(ws + 786432);        //   65536 B
    float*          bgp   = (float*)(ws + 851968);                 //    4096 B
    float*          bop   = (float*)(ws + 856064);                 //     512 B
    unsigned int*   flags = (unsigned int*)(ws + 856576);          //    4096 B
    unsigned short* hbuf  = (unsigned short*)(ws + 860672);        // 2097152 B (2 parity buffers)
    // total ws use: 2957824 B

    prep_kernel<<<1673, 256, 0, stream>>>(Wih, Whh, bih, bhh, Wcat, bcat, Wval, bval,
                                          Wg, Wo, bgp, bop, flags);
    rnn_kernel<<<256, 512, 32768, stream>>>(seq, Wg, Wo, bgp, bop, hbuf, flags, (float*)d_out);
}